// Round 9
// baseline (307.175 us; speedup 1.0000x reference)
//
#include <hip/hip_runtime.h>

// KMeans assignment: costs[i] = min_k ||x_i-c_k||^2, indices[i] = argmin_k.
// R9: SCREEN-THEN-RESCAN.
//  Phase 1: 1-pass f16 MFMA (xh.ch) over all 1024 centers, tracking per-point
//   (v1,i1,v2). Rigorous error bound: |s~ - s| <= 2(|xl||c| + |x||cl|+|xl||cl|)
//   via Cauchy-Schwarz with measured norms (Cmax/CLmax from prep). If
//   v2 > v1 + M, i1 is PROVABLY the exact argmin. Cost tolerance is 20.48 so
//   approx costs (err<=0.3) pass directly.
//  Rescan: flagged points (~5%) -> worklist -> gathered split-f16 3-pass exact
//   kernel (R5 clone, err ~1e-6) overwrites their outputs.
// Allocator wall (R3/R4/R7/R8): >128 arch VGPRs spill. Phase 1 needs only
// bh ping-pong 32 + ah 16 + slots 48 -> fits. LDS 37 KB -> 3 blocks/CU.
// N=131072, D=128, K=1024.  d_out = [costs (N f32), indices-as-f32 (N)].

typedef _Float16 f16x8 __attribute__((ext_vector_type(8)));
typedef float    f32x4 __attribute__((ext_vector_type(4)));
typedef unsigned short u16;
typedef unsigned int   u32;

constexpr int N = 131072, D = 128, K = 1024;
constexpr int MT = 128;

union H2U { _Float16 h; unsigned short u; };

__device__ inline void gl_lds16(const void* g, void* l) {
  __builtin_amdgcn_global_load_lds(
      (const __attribute__((address_space(1))) unsigned int*)g,
      (__attribute__((address_space(3))) unsigned int*)l, 16, 0, 0);
}

// ---- prep: centers -> hi/lo f16 tiled + exact c2 + global max norms ----
// ushort idx: (((cb*4 + kc)*4 + q)*128 + c%128)*8 + j, k = kc*32 + q*8 + j
__global__ void prep_centers(const float* __restrict__ centers,
                             u16* __restrict__ Bh, u16* __restrict__ Bl,
                             float* __restrict__ c2, u32* __restrict__ scal) {
  const int wave = threadIdx.x >> 6, lane = threadIdx.x & 63;
  const int c = blockIdx.x * 4 + wave;
  const float2 v = ((const float2*)(centers + (size_t)c * D))[lane];

  H2U h0, h1, l0, l1;
  h0.h = (_Float16)v.x;  float r0 = v.x - (float)h0.h;  l0.h = (_Float16)r0;
  h1.h = (_Float16)v.y;  float r1 = v.y - (float)h1.h;  l1.h = (_Float16)r1;

  float s  = v.x * v.x + v.y * v.y;
  float sl = r0 * r0 + r1 * r1;
  #pragma unroll
  for (int off = 32; off; off >>= 1) {
    s  += __shfl_xor(s, off, 64);
    sl += __shfl_xor(sl, off, 64);
  }
  if (lane == 0) {
    c2[c] = s;
    atomicMax(&scal[0], __float_as_uint(s));    // max ||c||^2  (positive)
    atomicMax(&scal[1], __float_as_uint(sl));   // max ||cl||^2
  }

  const int cb = c >> 7, cm = c & 127;
  const int kc = lane >> 4, q = (lane >> 2) & 3, j0 = (lane & 3) * 2;
  const size_t off = (((size_t)(cb * 4 + kc) * 4 + q) * 128 + cm) * 8 + j0;
  *(unsigned*)(Bh + off) = (unsigned)h0.u | ((unsigned)h1.u << 16);
  *(unsigned*)(Bl + off) = (unsigned)l0.u | ((unsigned)l1.u << 16);
}

// ---- phase 1: 1-pass screen, barrier-free K-loop, 3 blocks/CU ----
__global__ void __launch_bounds__(256, 3) kmeans_p1(
    const float* __restrict__ x, const u16* __restrict__ Bh_g,
    const float* __restrict__ c2g, const u32* __restrict__ scal,
    u32* __restrict__ cnt, u32* __restrict__ worklist,
    float* __restrict__ out_cost, float* __restrict__ out_idx)
{
  __shared__ __align__(16) u16 Ah[16384];   // [kc4][q4][m128][j8]  32 KB
  __shared__ float x2l[128], Ml[128];
  __shared__ float redA[256]; __shared__ int redB[256]; __shared__ float redC[256];

  const int tid = threadIdx.x;
  const int wave = tid >> 6, lane = tid & 63;
  const int wr = wave >> 1, wc = wave & 1;
  const int q = lane >> 4, ln = lane & 15;
  const int m0 = blockIdx.x * MT;

  const float cmax  = sqrtf(__uint_as_float(scal[0]));
  const float clmax = sqrtf(__uint_as_float(scal[1]));

  // ---- stage A-hi + per-point norms (thread pair owns one row) ----
  {
    const int m = tid >> 1, half = (tid & 1) * 64;
    const float* xrow = x + (size_t)(m0 + m) * D + half;
    float x2p = 0.f, xl2p = 0.f;
    #pragma unroll
    for (int i = 0; i < 16; ++i) {
      const float4 v = *(const float4*)(xrow + i * 4);
      const int k0 = half + i * 4;
      const int kq = k0 >> 5, qq = (k0 >> 3) & 3, j0 = k0 & 7;
      const float vv[4] = {v.x, v.y, v.z, v.w};
      H2U h[4];
      #pragma unroll
      for (int z = 0; z < 4; ++z) {
        h[z].h = (_Float16)vv[z];
        const float l = vv[z] - (float)h[z].h;
        x2p  += vv[z] * vv[z];
        xl2p += l * l;
      }
      uint2 hp;
      hp.x = h[0].u | ((unsigned)h[1].u << 16);
      hp.y = h[2].u | ((unsigned)h[3].u << 16);
      *(uint2*)(Ah + ((kq * 4 + qq) * 128 + m) * 8 + j0) = hp;
    }
    const float ox2 = __shfl_xor(x2p, 1, 64);
    const float oxl = __shfl_xor(xl2p, 1, 64);
    if ((tid & 1) == 0) {
      const float X2 = x2p + ox2, XL2 = xl2p + oxl;
      x2l[m] = X2;
      const float xn = sqrtf(X2), xln = sqrtf(XL2);
      // M = 2*bound(s~), bound = 2*(|xl||c| + |x||cl| + |xl||cl|) + eps
      Ml[m] = 4.f * (xln * cmax + xn * clmax + xln * clmax) + 0.05f;
    }
  }
  __syncthreads();   // A read-only from here; no more barriers until reduce

  const size_t laneB = ((size_t)q * 128 + wc * 64 + ln) * 8;
  const u16* bhP = Bh_g + laneB;

  float v1[16], v2[16]; int i1[16];
  #pragma unroll
  for (int b = 0; b < 16; ++b) { v1[b] = 3.4e38f; v2[b] = 3.4e38f; i1[b] = 0; }

  f16x8 bhS[2][4];
  #pragma unroll
  for (int t = 0; t < 4; ++t) bhS[0][t] = *(const f16x8*)(bhP + t * 128);

  for (int ct = 0; ct < 8; ++ct) {
    f32x4 acc[4][4];
    #pragma unroll
    for (int mt = 0; mt < 4; ++mt)
      #pragma unroll
      for (int nt = 0; nt < 4; ++nt)
        acc[mt][nt] = (f32x4){0.f, 0.f, 0.f, 0.f};

    float c2v[4];
    #pragma unroll
    for (int nt = 0; nt < 4; ++nt)
      c2v[nt] = c2g[ct * 128 + wc * 64 + nt * 16 + ln];

    #pragma unroll
    for (int kc = 0; kc < 4; ++kc) {
      const int cc = ct * 4 + kc;
      const int cur = kc & 1, nxt = cur ^ 1;
      if (kc < 3 || ct < 7) {                  // prefetch next chunk's bh
        const size_t goff = (size_t)(cc + 1) * 4096;
        #pragma unroll
        for (int t = 0; t < 4; ++t)
          bhS[nxt][t] = *(const f16x8*)(bhP + goff + t * 128);
      }
      f16x8 ah[4];
      #pragma unroll
      for (int t = 0; t < 4; ++t)
        ah[t] = *(const f16x8*)(Ah + ((kc * 4 + q) * 128 + wr * 64 + t * 16 + ln) * 8);
      #pragma unroll
      for (int mt = 0; mt < 4; ++mt)
        #pragma unroll
        for (int nt = 0; nt < 4; ++nt)
          acc[mt][nt] = __builtin_amdgcn_mfma_f32_16x16x32_f16(ah[mt], bhS[cur][nt], acc[mt][nt], 0, 0, 0);
    }

    #pragma unroll
    for (int nt = 0; nt < 4; ++nt) {
      const int n = ct * 128 + wc * 64 + nt * 16 + ln;
      #pragma unroll
      for (int mt = 0; mt < 4; ++mt)
        #pragma unroll
        for (int r = 0; r < 4; ++r) {
          const float s = __builtin_fmaf(-2.f, acc[mt][nt][r], c2v[nt]);
          const int b = mt * 4 + r;
          if (s < v1[b]) { v2[b] = v1[b]; v1[b] = s; i1[b] = n; }
          else if (s < v2[b]) v2[b] = s;
        }
    }
  }

  // ---- reduce (v1,i1,v2) across 16 ln-lanes sharing each row ----
  #pragma unroll
  for (int b = 0; b < 16; ++b) {
    float a1 = v1[b], a2 = v2[b]; int ai = i1[b];
    #pragma unroll
    for (int off = 1; off < 16; off <<= 1) {
      const float o1 = __shfl_xor(a1, off, 64);
      const float o2 = __shfl_xor(a2, off, 64);
      const int   oi = __shfl_xor(ai, off, 64);
      float n2;
      if (o1 < a1 || (o1 == a1 && oi < ai)) { n2 = fminf(a1, o2); a1 = o1; ai = oi; }
      else                                   { n2 = fminf(o1, a2); }
      a2 = n2;
    }
    v1[b] = a1; v2[b] = a2; i1[b] = ai;
  }
  if (ln == 0) {
    #pragma unroll
    for (int b = 0; b < 16; ++b) {
      const int ml = wr * 64 + (b >> 2) * 16 + q * 4 + (b & 3);
      redA[ml * 2 + wc] = v1[b];
      redB[ml * 2 + wc] = i1[b];
      redC[ml * 2 + wc] = v2[b];
    }
  }
  __syncthreads();
  if (tid < MT) {
    float a1 = redA[tid * 2], a2 = redC[tid * 2]; int ai = redB[tid * 2];
    const float o1 = redA[tid * 2 + 1], o2 = redC[tid * 2 + 1];
    const int   oi = redB[tid * 2 + 1];
    float n2;
    if (o1 < a1 || (o1 == a1 && oi < ai)) { n2 = fminf(a1, o2); a1 = o1; ai = oi; }
    else                                   { n2 = fminf(o1, a2); }
    a2 = n2;

    float cost = x2l[tid] + a1;
    if (cost < 0.f) cost = 0.f;
    out_cost[m0 + tid] = cost;
    out_idx[m0 + tid]  = (float)ai;
    if (a2 <= a1 + Ml[tid]) {                 // not provably exact -> rescan
      const u32 slot = atomicAdd(cnt, 1u);
      worklist[slot] = (u32)(m0 + tid);
    }
  }
}

// ---- rescan: gathered split-f16 3-pass exact (R5 clone), overwrites ----
__global__ void __launch_bounds__(256, 2) kmeans_rescan(
    const float* __restrict__ x,
    const u16* __restrict__ Bh_g, const u16* __restrict__ Bl_g,
    const float* __restrict__ c2g, const u32* __restrict__ cnt,
    const u32* __restrict__ worklist,
    float* __restrict__ out_cost, float* __restrict__ out_idx)
{
  __shared__ __align__(16) u16 smem[40960];   // A 64 KB + Bh dbuf 16 KB
  __shared__ int pidl[128];
  u16* Ah = smem;
  u16* Al = smem + 16384;

  const int tid = threadIdx.x;
  const int wave = tid >> 6, lane = tid & 63;
  const int wr = wave >> 1, wc = wave & 1;
  const int q = lane >> 4, ln = lane & 15;
  const int count = (int)cnt[0];

  for (int g = blockIdx.x; ; g += 128) {
    const int base = g * MT;
    if (base >= count) break;
    __syncthreads();                          // smem safe to reuse
    if (tid < 128) {
      int wi = base + tid; if (wi >= count) wi = count - 1;
      pidl[tid] = (int)worklist[wi];
    }
    __syncthreads();

    #pragma unroll
    for (int i = 0; i < 16; ++i) {
      const int flat = i * 256 + tid;
      const int m = flat >> 5, c4 = flat & 31, k0 = c4 * 4;
      const float4 v = *(const float4*)(x + (size_t)pidl[m] * D + k0);
      const int kc = k0 >> 5, qq = (k0 >> 3) & 3, j0 = k0 & 7;
      const float vv[4] = {v.x, v.y, v.z, v.w};
      H2U h[4], l[4];
      #pragma unroll
      for (int z = 0; z < 4; ++z) {
        h[z].h = (_Float16)vv[z];
        l[z].h = (_Float16)(vv[z] - (float)h[z].h);
      }
      const int off = ((kc * 4 + qq) * 128 + m) * 8 + j0;
      uint2 hp, lp;
      hp.x = h[0].u | ((unsigned)h[1].u << 16); hp.y = h[2].u | ((unsigned)h[3].u << 16);
      lp.x = l[0].u | ((unsigned)l[1].u << 16); lp.y = l[2].u | ((unsigned)l[3].u << 16);
      *(uint2*)(Ah + off) = hp;
      *(uint2*)(Al + off) = lp;
    }
    __syncthreads();

    float x2m = 0.f;
    if (tid < 128) {
      #pragma unroll
      for (int kq = 0; kq < 16; ++kq) {
        const f16x8 hv = *(const f16x8*)(Ah + (kq * 128 + tid) * 8);
        const f16x8 lv = *(const f16x8*)(Al + (kq * 128 + tid) * 8);
        #pragma unroll
        for (int e = 0; e < 8; ++e) {
          const float xv = (float)hv[e] + (float)lv[e];
          x2m += xv * xv;
        }
      }
    }

    const size_t laneB = ((size_t)q * 128 + wc * 64 + ln) * 8;
    const u16* blP = Bl_g + laneB;

    float bestV[16]; int bestI[16];
    #pragma unroll
    for (int b = 0; b < 16; ++b) { bestV[b] = 3.4e38f; bestI[b] = 0; }

    // Bh staged to LDS dbuf, one barrier/chunk; bl register ping-pong (R5)
    {
      const size_t eoffb = (size_t)wave * 512;
      #pragma unroll
      for (int i = 0; i < 2; ++i)
        gl_lds16(Bh_g + (size_t)i * 2048 + eoffb + (size_t)lane * 8,
                 smem + 32768 + i * 2048 + eoffb);
    }
    f16x8 blc[4], bln[4];
    #pragma unroll
    for (int t = 0; t < 4; ++t) blc[t] = *(const f16x8*)(blP + t * 128);

    for (int ct = 0; ct < 8; ++ct) {
      f32x4 acc[4][4];
      #pragma unroll
      for (int mt = 0; mt < 4; ++mt)
        #pragma unroll
        for (int nt = 0; nt < 4; ++nt)
          acc[mt][nt] = (f32x4){0.f, 0.f, 0.f, 0.f};

      float c2v[4];
      #pragma unroll
      for (int nt = 0; nt < 4; ++nt)
        c2v[nt] = c2g[ct * 128 + wc * 64 + nt * 16 + ln];

      #pragma unroll
      for (int kc = 0; kc < 4; ++kc) {
        const int cc = ct * 4 + kc;
        __syncthreads();
        if (cc < 31) {
          const size_t gbase = (size_t)(cc + 1) * 4096;
          u16* buf = smem + 32768 + ((cc + 1) & 1) * 4096;
          const size_t eoffb = (size_t)wave * 512;
          #pragma unroll
          for (int i = 0; i < 2; ++i)
            gl_lds16(Bh_g + gbase + (size_t)i * 2048 + eoffb + (size_t)lane * 8,
                     buf + i * 2048 + eoffb);
          #pragma unroll
          for (int t = 0; t < 4; ++t)
            bln[t] = *(const f16x8*)(blP + gbase + t * 128);
        }
        const u16* buf = smem + 32768 + (cc & 1) * 4096;

        f16x8 ah[4], al[4], bh[4];
        #pragma unroll
        for (int t = 0; t < 4; ++t) {
          const int moff = ((kc * 4 + q) * 128 + wr * 64 + t * 16 + ln) * 8;
          ah[t] = *(const f16x8*)(Ah + moff);
          al[t] = *(const f16x8*)(Al + moff);
          bh[t] = *(const f16x8*)(buf + (q * 128 + wc * 64 + t * 16 + ln) * 8);
        }
        #pragma unroll
        for (int mt = 0; mt < 4; ++mt)
          #pragma unroll
          for (int nt = 0; nt < 4; ++nt)
            acc[mt][nt] = __builtin_amdgcn_mfma_f32_16x16x32_f16(ah[mt], bh[nt], acc[mt][nt], 0, 0, 0);
        #pragma unroll
        for (int mt = 0; mt < 4; ++mt)
          #pragma unroll
          for (int nt = 0; nt < 4; ++nt)
            acc[mt][nt] = __builtin_amdgcn_mfma_f32_16x16x32_f16(al[mt], bh[nt], acc[mt][nt], 0, 0, 0);
        #pragma unroll
        for (int mt = 0; mt < 4; ++mt)
          #pragma unroll
          for (int nt = 0; nt < 4; ++nt)
            acc[mt][nt] = __builtin_amdgcn_mfma_f32_16x16x32_f16(ah[mt], blc[nt], acc[mt][nt], 0, 0, 0);
        #pragma unroll
        for (int t = 0; t < 4; ++t) blc[t] = bln[t];
      }

      #pragma unroll
      for (int nt = 0; nt < 4; ++nt) {
        const int n = ct * 128 + wc * 64 + nt * 16 + ln;
        #pragma unroll
        for (int mt = 0; mt < 4; ++mt)
          #pragma unroll
          for (int r = 0; r < 4; ++r) {
            const float s = __builtin_fmaf(-2.f, acc[mt][nt][r], c2v[nt]);
            const int b = mt * 4 + r;
            if (s < bestV[b]) { bestV[b] = s; bestI[b] = n; }
          }
      }
    }

    #pragma unroll
    for (int b = 0; b < 16; ++b) {
      float v = bestV[b]; int idx = bestI[b];
      #pragma unroll
      for (int off = 1; off < 16; off <<= 1) {
        const float ov = __shfl_xor(v, off, 64);
        const int   oi = __shfl_xor(idx, off, 64);
        if (ov < v || (ov == v && oi < idx)) { v = ov; idx = oi; }
      }
      bestV[b] = v; bestI[b] = idx;
    }

    __syncthreads();
    float* redV = (float*)(smem + 32768);
    int*   redI = (int*)(smem + 33280);
    if (ln == 0) {
      #pragma unroll
      for (int b = 0; b < 16; ++b) {
        const int ml = wr * 64 + (b >> 2) * 16 + q * 4 + (b & 3);
        redV[ml * 2 + wc] = bestV[b];
        redI[ml * 2 + wc] = bestI[b];
      }
    }
    __syncthreads();
    if (tid < 128 && base + tid < count) {
      float v = redV[tid * 2]; int idx = redI[tid * 2];
      const float v1 = redV[tid * 2 + 1]; const int i1 = redI[tid * 2 + 1];
      if (v1 < v || (v1 == v && i1 < idx)) { v = v1; idx = i1; }
      float cost = x2m + v;
      if (cost < 0.f) cost = 0.f;
      const int p = pidl[tid];
      out_cost[p] = cost;
      out_idx[p]  = (float)idx;
    }
  }
}

extern "C" void kernel_launch(void* const* d_in, const int* in_sizes, int n_in,
                              void* d_out, int out_size, void* d_ws, size_t ws_size,
                              hipStream_t stream) {
  const float* x       = (const float*)d_in[0];
  const float* centers = (const float*)d_in[1];
  u16*   Bh = (u16*)d_ws;                      // 256 KB
  u16*   Bl = Bh + (size_t)K * D;              // 256 KB
  float* c2 = (float*)(Bl + (size_t)K * D);    // 4 KB
  u32*   scal = (u32*)(c2 + K);                // [0]=cmax2 [1]=clmax2 [2]=count
  u32*   worklist = scal + 64;                 // 512 KB
  float* out_cost = (float*)d_out;
  float* out_idx  = out_cost + N;

  hipMemsetAsync(scal, 0, 256, stream);
  prep_centers<<<K / 4, 256, 0, stream>>>(centers, Bh, Bl, c2, scal);
  kmeans_p1<<<N / MT, 256, 0, stream>>>(x, Bh, c2, scal, &scal[2], worklist,
                                        out_cost, out_idx);
  kmeans_rescan<<<128, 256, 0, stream>>>(x, Bh, Bl, c2, &scal[2], worklist,
                                         out_cost, out_idx);
}